// Round 4
// baseline (3654.597 us; speedup 1.0000x reference)
//
#include <hip/hip_runtime.h>
#include <hip/hip_bf16.h>
#include <cstdint>

typedef __attribute__((ext_vector_type(8))) short short8;
typedef __attribute__((ext_vector_type(4))) short short4v;
typedef __attribute__((ext_vector_type(4))) float f32x4;
typedef unsigned short ushortT;

#define SEQ 200
#define NB  256

__device__ __forceinline__ float b2f(ushortT u){
    union { unsigned u; float f; } v; v.u = ((unsigned)u) << 16; return v.f;
}
__device__ __forceinline__ ushortT f2b(float f){
    union { float f; unsigned u; } v; v.f = f;
    unsigned r = v.u + 0x7FFFu + ((v.u >> 16) & 1u);
    return (ushortT)(r >> 16);
}
// fast reciprocal: ~1 ulp, far below bf16 rounding; avoids the full div sequence
__device__ __forceinline__ float frcp(float x){
    float r; asm("v_rcp_f32 %0, %1" : "=v"(r) : "v"(x)); return r;
}
__device__ __forceinline__ float sigm(float x){ return frcp(1.0f + __expf(-x)); }
__device__ __forceinline__ float tanh_fast(float x){
    float ax = fabsf(x);
    float t = __expf(-2.0f * ax);
    float r = (1.0f - t) * frcp(1.0f + t);
    return copysignf(r, x);
}

// ---- f32 -> bf16 bulk convert (n multiple of 1024) ----
__global__ void k_cvt(const float* __restrict__ in, ushortT* __restrict__ out){
    size_t i = ((size_t)blockIdx.x*256 + threadIdx.x)*4;
    float4 v = *(const float4*)(in + i);
    ushortT o[4] = { f2b(v.x), f2b(v.y), f2b(v.z), f2b(v.w) };
    *(int2*)(out + i) = *(int2*)o;
}

// ---- swizzle a (K x ncols) f32 row-major matrix into bf16 MFMA B-fragment tiles ----
// tile T (16 cols), kstep q (32 k): lane l holds B[k = q*32+(l>>4)*8+j][n = T*16+(l&15)], j=0..7
__global__ void k_swizzle(const float* __restrict__ src, int ncols,
                          ushortT* __restrict__ dst, int tile0){
    int Tl = blockIdx.x, q = blockIdx.y, l = threadIdx.x;
    int n  = Tl*16 + (l & 15);
    int kb = q*32 + (l >> 4)*8;
    short8 v;
    #pragma unroll
    for (int j = 0; j < 8; ++j) ((ushortT*)&v)[j] = f2b(src[(size_t)(kb + j)*ncols + n]);
    *(short8*)(dst + ((size_t)(tile0 + Tl)*8 + q)*512 + (size_t)l*8) = v;
}

// ---- tft = 1 - tanh((t/180*selw+selb)^2), stored as scan A-fragments (bf16) ----
__global__ void k_tft(const float* __restrict__ sts, const float* __restrict__ selw,
                      const float* __restrict__ selb, ushortT* __restrict__ tft){
    int l = threadIdx.x, g = blockIdx.x / SEQ, t = blockIdx.x % SEQ;
    int lm = l & 15, lq = l >> 4;
    float tv = sts[(size_t)(g*16 + lm)*SEQ + t] * (1.0f/180.0f);
    size_t base = (size_t)(g*SEQ + t)*1024 + (size_t)l*8;
    #pragma unroll
    for (int q = 0; q < 2; ++q){
        short8 v;
        #pragma unroll
        for (int j = 0; j < 8; ++j){
            int u = q*32 + lq*8 + j;
            float a = tv * selw[u] + selb[u];
            ((ushortT*)&v)[j] = f2b(1.0f - tanh_fast(a*a));
        }
        *(short8*)(tft + base + (size_t)q*512) = v;
    }
}

// ---- generic C[rows x 256] = A[rows x 256] @ Bswz(16 tiles) + bias(f32), bf16 out ----
__global__ __launch_bounds__(512) void k_gemm256(const ushortT* A,
        const ushortT* __restrict__ Bswz, const float* __restrict__ bias, ushortT* out){
    __shared__ ushortT stage[16*256];
    int tid = threadIdx.x, w = tid >> 6, l = tid & 63, lm = l & 15, lq = l >> 4;
    size_t r0 = (size_t)blockIdx.x * 16;
    const f32x4 fz = {0.f,0.f,0.f,0.f};
    f32x4 acc[2] = {fz, fz};
    for (int q = 0; q < 8; ++q){
        short8 a = *(const short8*)(A + (r0 + lm)*256 + q*32 + lq*8);
        #pragma unroll
        for (int p = 0; p < 2; ++p){
            int T = 2*w + p;
            short8 b = *(const short8*)(Bswz + ((size_t)T*8 + q)*512 + (size_t)l*8);
            acc[p] = __builtin_amdgcn_mfma_f32_16x16x32_bf16(a, b, acc[p], 0, 0, 0);
        }
    }
    #pragma unroll
    for (int p = 0; p < 2; ++p){
        int n = (2*w + p)*16 + lm;
        float bs = bias[n];
        #pragma unroll
        for (int r = 0; r < 4; ++r)
            stage[(lq*4 + r)*256 + n] = f2b(acc[p][r] + bs);
    }
    __syncthreads();
    int row = tid >> 5, c8 = tid & 31;
    int4 v = *(const int4*)(stage + row*256 + c8*8);
    *(int4*)(out + (r0 + row)*256 + (size_t)c8*8) = v;
}

// ---- gates pre-act: xg = A@Uall + (Wall_b+Uall_b), written in scan per-lane order ----
__global__ __launch_bounds__(512) void k_gemmgates(const ushortT* __restrict__ A,
        const ushortT* __restrict__ Bswz, const float* __restrict__ bW,
        const float* __restrict__ bU, ushortT* __restrict__ out){
    int tid = threadIdx.x, w = tid >> 6, l = tid & 63, lm = l & 15, lq = l >> 4;
    int g = blockIdx.x / SEQ, t = blockIdx.x % SEQ;
    const f32x4 fz = {0.f,0.f,0.f,0.f};
    f32x4 acc[8] = {fz,fz,fz,fz,fz,fz,fz,fz};
    const ushortT* Arow = A + ((size_t)(g*16 + lm)*SEQ + t)*256;
    for (int q = 0; q < 8; ++q){
        short8 a = *(const short8*)(Arow + q*32 + lq*8);
        #pragma unroll
        for (int gq = 0; gq < 4; ++gq)
        #pragma unroll
        for (int p = 0; p < 2; ++p){
            int T = gq*16 + 2*w + p;
            short8 b = *(const short8*)(Bswz + ((size_t)T*8 + q)*512 + (size_t)l*8);
            acc[gq*2+p] = __builtin_amdgcn_mfma_f32_16x16x32_bf16(a, b, acc[gq*2+p], 0, 0, 0);
        }
    }
    short8 ch[4];
    #pragma unroll
    for (int gq = 0; gq < 4; ++gq)
    #pragma unroll
    for (int p = 0; p < 2; ++p){
        int n = gq*256 + w*32 + p*16 + lm;
        float bs = bW[n] + bU[n];
        #pragma unroll
        for (int r = 0; r < 4; ++r)
            ((ushortT*)&ch[p*2 + (gq>>1)])[(gq&1)*4 + r] = f2b(acc[gq*2+p][r] + bs);
    }
    size_t base = (size_t)(g*SEQ + t)*16384 + (size_t)(w*64 + l)*32;
    #pragma unroll
    for (int ci = 0; ci < 4; ++ci) *(short8*)(out + base + ci*8) = ch[ci];
}

// ---- zero the exchange flags (fresh per launch) ----
__global__ void k_zeroflags(unsigned* __restrict__ f){
    f[blockIdx.x*256 + threadIdx.x] = 0;
}

// ---- persistent TLSTM scan: 32 WGs (2 per batch-group), 512 threads / 8 waves each ----
// WG (h,g): h = blk>>4, g = blk&15 (pair on same XCD). Wave w owns cols cw=h*8+w.
// Weights fully resident (gq0,1,2+Wd in AGPR/VGPR, gq3 in LDS). Exchange is PIPELINED:
// local-half MFMA runs before the partner-slice spin/import; export is reg-scatter
// (h,c packed u32) so only 2 barriers/step sit on the critical path.
#define HB (16*264)
__global__ __launch_bounds__(512, 2) void k_scan(const ushortT* __restrict__ xg,
        const ushortT* __restrict__ tftg, const ushortT* __restrict__ Wswz,
        const ushortT* __restrict__ twswz, const float* __restrict__ wdb_g,
        const float* __restrict__ timeb, ushortT* __restrict__ hs,
        float* __restrict__ maxh, int write_hs,
        ushortT* __restrict__ xbuf, unsigned* __restrict__ flags, unsigned fb){
    extern __shared__ ushortT smem[];
    // layout: hbuf[2] = smem[0..2*HB), cbuf[2] = smem[2*HB..4*HB), wlds = smem[4*HB..)
    ushortT* wlds = smem + 4*HB;
    int tid = threadIdx.x, w = tid >> 6, l = tid & 63, lm = l & 15, lq = l >> 4;
    int blk = blockIdx.x;
    int h = blk >> 4, g = blk & 15;
    int pblk = (1 - h)*16 + g;           // partner block
    int cw = h*8 + w;                    // global 16-col tile index 0..15
    int col = cw*16 + lm;
    int l8 = l*8;
    int qlo = h*4;                       // local K-half  (my columns feed these q's)
    int qro = (1 - h)*4;                 // remote K-half (partner columns)
    float wdb = wdb_g[col];
    float tb  = timeb[col];
    short8 twf[2];
    #pragma unroll
    for (int q2 = 0; q2 < 2; ++q2)
        twf[q2] = *(const short8*)(twswz + ((size_t)cw*8 + q2)*512 + l8);
    // resident weight tiles: gates gq=0,1,2 and Wd in registers (AGPR-eligible)
    short8 wg0[8], wg1[8], wg2[8], wdreg[8];
    #pragma unroll
    for (int q = 0; q < 8; ++q){
        wg0[q]   = *(const short8*)(Wswz + ((size_t)( 0 + cw)*8 + q)*512 + l8);
        wg1[q]   = *(const short8*)(Wswz + ((size_t)(16 + cw)*8 + q)*512 + l8);
        wg2[q]   = *(const short8*)(Wswz + ((size_t)(32 + cw)*8 + q)*512 + l8);
        wdreg[q] = *(const short8*)(Wswz + ((size_t)(64 + cw)*8 + q)*512 + l8);
    }
    float c[4], hm[4];
    #pragma unroll
    for (int i = 0; i < 4; ++i){ c[i] = 0.0f; hm[i] = -2.0f; }
    // zero buffer 1 (read at t=0), both halves of h and c
    for (int i = tid; i < HB; i += 512){ smem[HB + i] = 0; smem[3*HB + i] = 0; }
    // preload gq=3 tiles for my 8 waves into LDS (tiles 48+h*8..+8, 64 KB)
    {
        const int4* wsrc = (const int4*)(Wswz + (size_t)(48 + h*8)*4096);
        int4* wdst = (int4*)wlds;
        for (int i = tid; i < 4096; i += 512) wdst[i] = wsrc[i];
    }
    __syncthreads();

    const ushortT* xg_g  = xg   + (size_t)g*SEQ*16384 + ((size_t)(cw>>1)*64 + l)*32 + (cw&1)*16;
    const ushortT* tft_g = tftg + (size_t)g*SEQ*1024  + (size_t)l8;
    const ushortT* wl    = wlds + (size_t)w*4096 + l8;
    const f32x4 fz = {0.f,0.f,0.f,0.f};

    for (int t = 0; t < SEQ; ++t){
        int pb = t & 1, ab = 1 - pb;
        ushortT* hb = smem + (size_t)ab*HB;
        ushortT* cb = smem + 2*HB + (size_t)ab*HB;
        // per-step inputs, issued early (consumed in elementwise)
        short8 xA  = *(const short8*)(xg_g + (size_t)t*16384);
        short8 xB  = *(const short8*)(xg_g + (size_t)t*16384 + 8);
        short8 aT0 = *(const short8*)(tft_g + (size_t)t*1024);
        short8 aT1 = *(const short8*)(tft_g + (size_t)t*1024 + 512);

        f32x4 acc[5];
        #pragma unroll
        for (int i = 0; i < 5; ++i) acc[i] = fz;
        // ---- local K-half MFMA (data barrier'd at end of previous step) ----
        #pragma unroll
        for (int qi = 0; qi < 4; ++qi){
            int q = qlo + qi;
            short8 a  = *(const short8*)(hb + lm*264 + q*32 + lq*8);
            short8 ca = *(const short8*)(cb + lm*264 + q*32 + lq*8);
            short8 b3 = *(const short8*)(wl + q*512);
            acc[0] = __builtin_amdgcn_mfma_f32_16x16x32_bf16(a,  wg0[q],   acc[0], 0, 0, 0);
            acc[1] = __builtin_amdgcn_mfma_f32_16x16x32_bf16(a,  wg1[q],   acc[1], 0, 0, 0);
            acc[2] = __builtin_amdgcn_mfma_f32_16x16x32_bf16(a,  wg2[q],   acc[2], 0, 0, 0);
            acc[3] = __builtin_amdgcn_mfma_f32_16x16x32_bf16(a,  b3,       acc[3], 0, 0, 0);
            acc[4] = __builtin_amdgcn_mfma_f32_16x16x32_bf16(ca, wdreg[q], acc[4], 0, 0, 0);
        }
        f32x4 acc_ts = fz;
        acc_ts = __builtin_amdgcn_mfma_f32_16x16x32_bf16(aT0, twf[0], acc_ts, 0, 0, 0);
        acc_ts = __builtin_amdgcn_mfma_f32_16x16x32_bf16(aT1, twf[1], acc_ts, 0, 0, 0);

        // ---- spin + import partner slice (hidden under the MFMA above) ----
        if (t > 0){
            unsigned want = fb + (unsigned)t;
            for (int it = 0; it < 20000000; ++it){
                if (__hip_atomic_load(&flags[(size_t)pblk*64],
                        __ATOMIC_ACQUIRE, __HIP_MEMORY_SCOPE_AGENT) >= want) break;
                __builtin_amdgcn_s_sleep(1);
            }
            int row = tid >> 5, seg = tid & 31;        // 512 thr x 16B = 8 KB slice
            const unsigned long long* src = (const unsigned long long*)(xbuf +
                ((size_t)(pblk*2 + ab)*16 + row)*256 + seg*8);
            unsigned long long u0 = __hip_atomic_load(src+0, __ATOMIC_RELAXED, __HIP_MEMORY_SCOPE_AGENT);
            unsigned long long u1 = __hip_atomic_load(src+1, __ATOMIC_RELAXED, __HIP_MEMORY_SCOPE_AGENT);
            ushortT* hdst = hb + row*264 + (1-h)*128 + seg*4;
            ushortT* cdst = cb + row*264 + (1-h)*128 + seg*4;
            short4v hv4, cv4;
            hv4[0] = (short)(ushortT)(u0);       cv4[0] = (short)(ushortT)(u0 >> 16);
            hv4[1] = (short)(ushortT)(u0 >> 32); cv4[1] = (short)(ushortT)(u0 >> 48);
            hv4[2] = (short)(ushortT)(u1);       cv4[2] = (short)(ushortT)(u1 >> 16);
            hv4[3] = (short)(ushortT)(u1 >> 32); cv4[3] = (short)(ushortT)(u1 >> 48);
            *(short4v*)hdst = hv4;
            *(short4v*)cdst = cv4;
            __syncthreads();                            // partner half visible in LDS
        }
        // ---- remote K-half MFMA ----
        #pragma unroll
        for (int qi = 0; qi < 4; ++qi){
            int q = qro + qi;
            short8 a  = *(const short8*)(hb + lm*264 + q*32 + lq*8);
            short8 ca = *(const short8*)(cb + lm*264 + q*32 + lq*8);
            short8 b3 = *(const short8*)(wl + q*512);
            acc[0] = __builtin_amdgcn_mfma_f32_16x16x32_bf16(a,  wg0[q],   acc[0], 0, 0, 0);
            acc[1] = __builtin_amdgcn_mfma_f32_16x16x32_bf16(a,  wg1[q],   acc[1], 0, 0, 0);
            acc[2] = __builtin_amdgcn_mfma_f32_16x16x32_bf16(a,  wg2[q],   acc[2], 0, 0, 0);
            acc[3] = __builtin_amdgcn_mfma_f32_16x16x32_bf16(a,  b3,       acc[3], 0, 0, 0);
            acc[4] = __builtin_amdgcn_mfma_f32_16x16x32_bf16(ca, wdreg[q], acc[4], 0, 0, 0);
        }

        ushortT* hbw = smem + (size_t)pb*HB;
        ushortT* cbw = smem + 2*HB + (size_t)pb*HB;
        #pragma unroll
        for (int r = 0; r < 4; ++r){
            float F   = acc[0][r] + b2f(((const ushortT*)&xA)[r]);
            float I   = acc[1][r] + b2f(((const ushortT*)&xA)[4+r]);
            float O   = acc[2][r] + b2f(((const ushortT*)&xB)[r]);
            float CT  = acc[3][r] + b2f(((const ushortT*)&xB)[4+r]);
            float cwd = acc[4][r] + wdb;
            float ts  = acc_ts[r] + tb;
            float cc  = c[r];
            float cs1 = tanh_fast(cwd);
            float cadj = cc - cs1 + cs1*ts;
            float cn  = sigm(F)*cadj + sigm(I)*sigm(CT);
            float hv  = sigm(O)*tanh_fast(cn);
            c[r]  = cn;
            hm[r] = fmaxf(hm[r], hv);
            ushortT hbf = f2b(hv), cbf = f2b(cn);
            hbw[(lq*4 + r)*264 + col] = hbf;
            cbw[(lq*4 + r)*264 + col] = cbf;
            if (t < SEQ-1){
                // reg-scatter export: one u32 {h,c} per element
                unsigned hc = (unsigned)hbf | ((unsigned)cbf << 16);
                unsigned* xd = (unsigned*)(xbuf +
                    ((size_t)(blk*2 + pb)*16 + (lq*4 + r))*256 + (size_t)(w*16 + lm)*2);
                __hip_atomic_store(xd, hc, __ATOMIC_RELAXED, __HIP_MEMORY_SCOPE_AGENT);
            }
        }
        __syncthreads();                                // LDS writes + export stores drained
        if (t < SEQ-1 && tid == 0)
            __hip_atomic_store(&flags[(size_t)blk*64], fb + (unsigned)t + 1u,
                               __ATOMIC_RELEASE, __HIP_MEMORY_SCOPE_AGENT);
        if (write_hs && tid < 256){
            int row = tid >> 4, c16 = tid & 15;
            int4 v = *(const int4*)(hbw + row*264 + h*128 + c16*8);
            *(int4*)(hs + ((size_t)(g*16 + row)*SEQ + t)*256 + h*128 + c16*8) = v;
        }
    }
    #pragma unroll
    for (int r = 0; r < 4; ++r)
        maxh[(size_t)(g*16 + lq*4 + r)*256 + col] = hm[r];
}

// ---- snapshot e_k = x[:,0,:] (bf16) ----
__global__ void k_ekcopy(const ushortT* __restrict__ x, ushortT* __restrict__ ek){
    int b = blockIdx.x, l = threadIdx.x;   // 64 threads, 4 ushorts each
    ((int2*)(ek + (size_t)b*256))[l] = ((const int2*)(x + (size_t)b*SEQ*256))[l];
}

// ---- e_k @ w1[0:256] + w1_b (f32 weights) ----
__global__ void k_ekw(const ushortT* __restrict__ ek, const float* __restrict__ w1w,
                      const float* __restrict__ w1b, float* __restrict__ ekw){
    int b = blockIdx.x, l = threadIdx.x;
    float acc = w1b[l];
    const ushortT* e = ek + (size_t)b*256;
    for (int d = 0; d < 256; ++d)
        acc += b2f(e[d]) * w1w[(size_t)d*64 + l];
    ekw[b*64 + l] = acc;
}

// ---- attention + aligned + gen_x, one wave per (b, s') ----
__global__ __launch_bounds__(512) void k_attn(const ushortT* __restrict__ ekbuf,
        const ushortT* __restrict__ whk, const float* __restrict__ ekw,
        const float* __restrict__ w1w, const float* __restrict__ w2w,
        const float* __restrict__ w2b, const float* __restrict__ nn,
        const float* __restrict__ pn, ushortT* __restrict__ genx){
    int w = threadIdx.x >> 6, l = threadIdx.x & 63;
    int wid = blockIdx.x*8 + w;
    int b = wid / SEQ, sp = wid % SEQ;
    const ushortT* ek = ekbuf + (size_t)b*256;
    const ushortT* wr = whk + ((size_t)b*SEQ + (sp > 0 ? sp-1 : 0))*256;
    size_t orow = ((size_t)b*SEQ + sp)*256;
    float a0, a1;
    if (sp == 0){ a0 = 1.0f; a1 = 0.0f; }
    else {
        float acc = ekw[b*64 + l];
        for (int d = 0; d < 256; ++d)
            acc += b2f(wr[d]) * w1w[(size_t)(256 + d)*64 + l];
        float u  = tanh_fast(acc);
        float p0 = u * w2w[l*2 + 0];
        float p1 = u * w2w[l*2 + 1];
        #pragma unroll
        for (int off = 32; off >= 1; off >>= 1){
            p0 += __shfl_xor(p0, off, 64);
            p1 += __shfl_xor(p1, off, 64);
        }
        float v0 = p0 + w2b[0], v1 = p1 + w2b[1];
        a0 = sigm(v0 - v1); a1 = 1.0f - a0;
    }
    #pragma unroll
    for (int i = 0; i < 4; ++i){
        int d = i*64 + l;
        float al = b2f(ek[d])*a0 + b2f(wr[d])*a1;
        float gv = al + nn[orow + d] - pn[orow + d];
        genx[orow + d] = f2b(gv);
    }
}

// ---- heads: out = maxh @ out_w + out_b (all f32) ----
__global__ void k_final(const float* __restrict__ mh1, const float* __restrict__ mh2,
                        const float* __restrict__ ow, const float* __restrict__ ob,
                        float* __restrict__ outp){
    int th = threadIdx.x;
    const float* mh = blockIdx.x ? mh2 : mh1;
    int b = th >> 1, cc = th & 1;
    float acc = ob[cc];
    for (int d = 0; d < 256; ++d)
        acc += mh[b*256 + d] * ow[d*2 + cc];
    outp[blockIdx.x*512 + th] = acc;
}

extern "C" void kernel_launch(void* const* d_in, const int* in_sizes, int n_in,
                              void* d_out, int out_size, void* d_ws, size_t ws_size,
                              hipStream_t stream) {
    const float* input_seqs = (const float*)d_in[0];
    const float* seq_time   = (const float*)d_in[3];
    const float* nn     = (const float*)d_in[6];
    const float* pn     = (const float*)d_in[7];
    const float* emb2_w = (const float*)d_in[9];
    const float* emb2_b = (const float*)d_in[10];
    const float* Wall_w = (const float*)d_in[11];
    const float* Wall_b = (const float*)d_in[12];
    const float* Uall_w = (const float*)d_in[13];
    const float* Uall_b = (const float*)d_in[14];
    const float* Wd_w   = (const float*)d_in[15];
    const float* Wd_b   = (const float*)d_in[16];
    const float* time_w = (const float*)d_in[17];
    const float* time_b = (const float*)d_in[18];
    const float* sel_w  = (const float*)d_in[19];
    const float* sel_b  = (const float*)d_in[20];
    const float* whk_w  = (const float*)d_in[21];
    const float* whk_b  = (const float*)d_in[22];
    const float* w1_w   = (const float*)d_in[23];
    const float* w1_b   = (const float*)d_in[24];
    const float* w2_w   = (const float*)d_in[25];
    const float* w2_b   = (const float*)d_in[26];
    const float* out_w  = (const float*)d_in[27];
    const float* out_b  = (const float*)d_in[28];

    const size_t NSZ = (size_t)in_sizes[6];   // B*SEQ*D noise element count

    // allow >64KB dynamic LDS for k_scan (160 KB/CU on gfx950)
    static bool attr_done = false;
    if (!attr_done){
        hipFuncSetAttribute((const void*)k_scan,
                            hipFuncAttributeMaxDynamicSharedMemorySize, 160*1024);
        attr_done = true;
    }
    const size_t SCAN_LDS = (size_t)(4*HB + 8*4096) * sizeof(ushortT);  // 99,328 B

    char* wsb = (char*)d_ws;
    size_t off = 0;
    auto alloc = [&](size_t bytes){ void* p = wsb + off; off += (bytes + 255) & ~(size_t)255; return p; };
    ushortT* Wswz  = (ushortT*)alloc(80u*8*512*2);     // Wall tiles 0..63, Wd tiles 64..79
    ushortT* Uswz  = (ushortT*)alloc(64u*8*512*2);
    ushortT* Eswz  = (ushortT*)alloc(16u*8*512*2);
    ushortT* Hswz  = (ushortT*)alloc(16u*8*512*2);
    ushortT* TWswz = (ushortT*)alloc(16u*8*512*2);     // time_w (only q=0,1 slots used)
    ushortT* TFT   = (ushortT*)alloc((size_t)16*SEQ*1024*2);   // 6.6 MB
    ushortT* X     = (ushortT*)alloc((size_t)NB*SEQ*256*2);    // 26.2 MB (reused as GENX)
    ushortT* XG    = (ushortT*)alloc((size_t)16*SEQ*16384*2);  // 100 MB
    ushortT* HS    = (ushortT*)alloc((size_t)NB*SEQ*256*2);    // 26.2 MB (also input bf16 staging)
    ushortT* EK    = (ushortT*)alloc((size_t)NB*256*2);
    float*  MAXH1  = (float*)alloc((size_t)NB*256*4);
    float*  MAXH2  = (float*)alloc((size_t)NB*256*4);
    float*  EKW    = (float*)alloc((size_t)NB*64*4);
    ushortT* XBUF  = (ushortT*)alloc((size_t)32*2*16*256*2);   // 512 KB pair-exchange {h,c}
    unsigned* FLAGS= (unsigned*)alloc((size_t)32*64*4);        // 8 KB, 256B-strided flags

    float* outp = (float*)d_out;
    // outputs 2,3 are pass-throughs (predicted_noise, normal_noise), f32
    hipMemcpyAsync(outp + 1024,       pn, NSZ*4, hipMemcpyDeviceToDevice, stream);
    hipMemcpyAsync(outp + 1024 + NSZ, nn, NSZ*4, hipMemcpyDeviceToDevice, stream);

    k_zeroflags<<<8, 256, 0, stream>>>(FLAGS);
    k_swizzle<<<dim3(64,8), 64, 0, stream>>>(Wall_w, 1024, Wswz, 0);
    k_swizzle<<<dim3(16,8), 64, 0, stream>>>(Wd_w,    256, Wswz, 64);
    k_swizzle<<<dim3(64,8), 64, 0, stream>>>(Uall_w, 1024, Uswz, 0);
    k_swizzle<<<dim3(16,8), 64, 0, stream>>>(emb2_w,  256, Eswz, 0);
    k_swizzle<<<dim3(16,8), 64, 0, stream>>>(whk_w,   256, Hswz, 0);
    k_swizzle<<<dim3(16,2), 64, 0, stream>>>(time_w,  256, TWswz, 0);  // K=64 → q<2

    k_tft<<<3200, 64, 0, stream>>>(seq_time, sel_w, sel_b, TFT);
    k_cvt<<<12800, 256, 0, stream>>>(input_seqs, HS);          // f32 input → bf16 (staged in HS)
    k_gemm256<<<3200, 512, 0, stream>>>(HS, Eswz, emb2_b, X);
    k_ekcopy<<<256, 64, 0, stream>>>(X, EK);
    k_ekw<<<256, 64, 0, stream>>>(EK, w1_w, w1_b, EKW);
    k_gemmgates<<<3200, 512, 0, stream>>>(X, Uswz, Wall_b, Uall_b, XG);
    k_scan<<<32, 512, SCAN_LDS, stream>>>(XG, TFT, Wswz, TWswz, Wd_b, time_b, HS, MAXH1, 1,
                                          XBUF, FLAGS, 0u);
    k_gemm256<<<3200, 512, 0, stream>>>(HS, Hswz, whk_b, HS);   // whk in-place (block-local rows)
    k_attn<<<6400, 512, 0, stream>>>(EK, HS, EKW, w1_w, w2_w, w2_b, nn, pn, X);  // genx → X region
    k_gemmgates<<<3200, 512, 0, stream>>>(X, Uswz, Wall_b, Uall_b, XG);
    k_scan<<<32, 512, SCAN_LDS, stream>>>(XG, TFT, Wswz, TWswz, Wd_b, time_b, HS, MAXH2, 0,
                                          XBUF, FLAGS, (unsigned)SEQ);
    k_final<<<2, 512, 0, stream>>>(MAXH1, MAXH2, out_w, out_b, outp);
}

// Round 5
// 3207.040 us; speedup vs baseline: 1.1396x; 1.1396x over previous
//
#include <hip/hip_runtime.h>
#include <hip/hip_bf16.h>
#include <cstdint>

typedef __attribute__((ext_vector_type(8))) short short8;
typedef __attribute__((ext_vector_type(4))) short short4v;
typedef __attribute__((ext_vector_type(4))) float f32x4;
typedef unsigned short ushortT;

#define SEQ 200
#define NB  256

__device__ __forceinline__ float b2f(ushortT u){
    union { unsigned u; float f; } v; v.u = ((unsigned)u) << 16; return v.f;
}
__device__ __forceinline__ ushortT f2b(float f){
    union { float f; unsigned u; } v; v.f = f;
    unsigned r = v.u + 0x7FFFu + ((v.u >> 16) & 1u);
    return (ushortT)(r >> 16);
}
// fast reciprocal: ~1 ulp, far below bf16 rounding; avoids the full div sequence
__device__ __forceinline__ float frcp(float x){
    float r; asm("v_rcp_f32 %0, %1" : "=v"(r) : "v"(x)); return r;
}
__device__ __forceinline__ float sigm(float x){ return frcp(1.0f + __expf(-x)); }
__device__ __forceinline__ float tanh_fast(float x){
    float ax = fabsf(x);
    float t = __expf(-2.0f * ax);
    float r = (1.0f - t) * frcp(1.0f + t);
    return copysignf(r, x);
}

// ---- f32 -> bf16 bulk convert (n multiple of 1024) ----
__global__ void k_cvt(const float* __restrict__ in, ushortT* __restrict__ out){
    size_t i = ((size_t)blockIdx.x*256 + threadIdx.x)*4;
    float4 v = *(const float4*)(in + i);
    ushortT o[4] = { f2b(v.x), f2b(v.y), f2b(v.z), f2b(v.w) };
    *(int2*)(out + i) = *(int2*)o;
}

// ---- swizzle a (K x ncols) f32 row-major matrix into bf16 MFMA B-fragment tiles ----
// tile T (16 cols), kstep q (32 k): lane l holds B[k = q*32+(l>>4)*8+j][n = T*16+(l&15)], j=0..7
__global__ void k_swizzle(const float* __restrict__ src, int ncols,
                          ushortT* __restrict__ dst, int tile0){
    int Tl = blockIdx.x, q = blockIdx.y, l = threadIdx.x;
    int n  = Tl*16 + (l & 15);
    int kb = q*32 + (l >> 4)*8;
    short8 v;
    #pragma unroll
    for (int j = 0; j < 8; ++j) ((ushortT*)&v)[j] = f2b(src[(size_t)(kb + j)*ncols + n]);
    *(short8*)(dst + ((size_t)(tile0 + Tl)*8 + q)*512 + (size_t)l*8) = v;
}

// ---- tft = 1 - tanh((t/180*selw+selb)^2), stored as scan A-fragments (bf16) ----
__global__ void k_tft(const float* __restrict__ sts, const float* __restrict__ selw,
                      const float* __restrict__ selb, ushortT* __restrict__ tft){
    int l = threadIdx.x, g = blockIdx.x / SEQ, t = blockIdx.x % SEQ;
    int lm = l & 15, lq = l >> 4;
    float tv = sts[(size_t)(g*16 + lm)*SEQ + t] * (1.0f/180.0f);
    size_t base = (size_t)(g*SEQ + t)*1024 + (size_t)l*8;
    #pragma unroll
    for (int q = 0; q < 2; ++q){
        short8 v;
        #pragma unroll
        for (int j = 0; j < 8; ++j){
            int u = q*32 + lq*8 + j;
            float a = tv * selw[u] + selb[u];
            ((ushortT*)&v)[j] = f2b(1.0f - tanh_fast(a*a));
        }
        *(short8*)(tft + base + (size_t)q*512) = v;
    }
}

// ---- generic C[rows x 256] = A[rows x 256] @ Bswz(16 tiles) + bias(f32), bf16 out ----
__global__ __launch_bounds__(512) void k_gemm256(const ushortT* A,
        const ushortT* __restrict__ Bswz, const float* __restrict__ bias, ushortT* out){
    __shared__ ushortT stage[16*256];
    int tid = threadIdx.x, w = tid >> 6, l = tid & 63, lm = l & 15, lq = l >> 4;
    size_t r0 = (size_t)blockIdx.x * 16;
    const f32x4 fz = {0.f,0.f,0.f,0.f};
    f32x4 acc[2] = {fz, fz};
    for (int q = 0; q < 8; ++q){
        short8 a = *(const short8*)(A + (r0 + lm)*256 + q*32 + lq*8);
        #pragma unroll
        for (int p = 0; p < 2; ++p){
            int T = 2*w + p;
            short8 b = *(const short8*)(Bswz + ((size_t)T*8 + q)*512 + (size_t)l*8);
            acc[p] = __builtin_amdgcn_mfma_f32_16x16x32_bf16(a, b, acc[p], 0, 0, 0);
        }
    }
    #pragma unroll
    for (int p = 0; p < 2; ++p){
        int n = (2*w + p)*16 + lm;
        float bs = bias[n];
        #pragma unroll
        for (int r = 0; r < 4; ++r)
            stage[(lq*4 + r)*256 + n] = f2b(acc[p][r] + bs);
    }
    __syncthreads();
    int row = tid >> 5, c8 = tid & 31;
    int4 v = *(const int4*)(stage + row*256 + c8*8);
    *(int4*)(out + (r0 + row)*256 + (size_t)c8*8) = v;
}

// ---- gates pre-act: xg = A@Uall + (Wall_b+Uall_b), written in scan per-lane order ----
__global__ __launch_bounds__(512) void k_gemmgates(const ushortT* __restrict__ A,
        const ushortT* __restrict__ Bswz, const float* __restrict__ bW,
        const float* __restrict__ bU, ushortT* __restrict__ out){
    int tid = threadIdx.x, w = tid >> 6, l = tid & 63, lm = l & 15, lq = l >> 4;
    int g = blockIdx.x / SEQ, t = blockIdx.x % SEQ;
    const f32x4 fz = {0.f,0.f,0.f,0.f};
    f32x4 acc[8] = {fz,fz,fz,fz,fz,fz,fz,fz};
    const ushortT* Arow = A + ((size_t)(g*16 + lm)*SEQ + t)*256;
    for (int q = 0; q < 8; ++q){
        short8 a = *(const short8*)(Arow + q*32 + lq*8);
        #pragma unroll
        for (int gq = 0; gq < 4; ++gq)
        #pragma unroll
        for (int p = 0; p < 2; ++p){
            int T = gq*16 + 2*w + p;
            short8 b = *(const short8*)(Bswz + ((size_t)T*8 + q)*512 + (size_t)l*8);
            acc[gq*2+p] = __builtin_amdgcn_mfma_f32_16x16x32_bf16(a, b, acc[gq*2+p], 0, 0, 0);
        }
    }
    short8 ch[4];
    #pragma unroll
    for (int gq = 0; gq < 4; ++gq)
    #pragma unroll
    for (int p = 0; p < 2; ++p){
        int n = gq*256 + w*32 + p*16 + lm;
        float bs = bW[n] + bU[n];
        #pragma unroll
        for (int r = 0; r < 4; ++r)
            ((ushortT*)&ch[p*2 + (gq>>1)])[(gq&1)*4 + r] = f2b(acc[gq*2+p][r] + bs);
    }
    size_t base = (size_t)(g*SEQ + t)*16384 + (size_t)(w*64 + l)*32;
    #pragma unroll
    for (int ci = 0; ci < 4; ++ci) *(short8*)(out + base + ci*8) = ch[ci];
}

// ---- zero the exchange flags (fresh per launch) ----
__global__ void k_zeroflags(unsigned* __restrict__ f){
    f[blockIdx.x*256 + threadIdx.x] = 0;
}

// ---- persistent TLSTM scan: 32 WGs (2 per batch-group), 512 threads / 8 waves each ----
// WG (h,g): h = blk>>4, g = blk&15 (pair on same XCD). Wave w owns cols cw=h*8+w.
// Weights fully resident (gq0,1,2+Wd in AGPR/VGPR, gq3 in LDS). Schedule pipelined:
// local K-half MFMA (my own columns) issues BEFORE the partner spin/import, hiding the
// handshake. Mechanics are R3's proven set: tid0-only acquire spin (1 L1-inval/step),
// int4 LDS-staged export (coalesced), relaxed int4 import.
#define HB (16*264)
__global__ __launch_bounds__(512, 2) void k_scan(const ushortT* __restrict__ xg,
        const ushortT* __restrict__ tftg, const ushortT* __restrict__ Wswz,
        const ushortT* __restrict__ twswz, const float* __restrict__ wdb_g,
        const float* __restrict__ timeb, ushortT* __restrict__ hs,
        float* __restrict__ maxh, int write_hs,
        ushortT* __restrict__ xbuf, unsigned* __restrict__ flags, unsigned fb){
    extern __shared__ ushortT smem[];
    // layout: hbuf[2] = smem[0..2*HB), cbuf[2] = smem[2*HB..4*HB), wlds = smem[4*HB..)
    ushortT* wlds = smem + 4*HB;
    int tid = threadIdx.x, w = tid >> 6, l = tid & 63, lm = l & 15, lq = l >> 4;
    int blk = blockIdx.x;
    int h = blk >> 4, g = blk & 15;
    int pblk = (1 - h)*16 + g;           // partner block
    int cw = h*8 + w;                    // global 16-col tile index 0..15
    int col = cw*16 + lm;
    int l8 = l*8;
    int qlo = h*4;                       // local K-half  (my columns feed these q's)
    int qro = (1 - h)*4;                 // remote K-half (partner columns)
    float wdb = wdb_g[col];
    float tb  = timeb[col];
    short8 twf[2];
    #pragma unroll
    for (int q2 = 0; q2 < 2; ++q2)
        twf[q2] = *(const short8*)(twswz + ((size_t)cw*8 + q2)*512 + l8);
    // resident weight tiles: gates gq=0,1,2 and Wd in registers (AGPR-eligible)
    short8 wg0[8], wg1[8], wg2[8], wdreg[8];
    #pragma unroll
    for (int q = 0; q < 8; ++q){
        wg0[q]   = *(const short8*)(Wswz + ((size_t)( 0 + cw)*8 + q)*512 + l8);
        wg1[q]   = *(const short8*)(Wswz + ((size_t)(16 + cw)*8 + q)*512 + l8);
        wg2[q]   = *(const short8*)(Wswz + ((size_t)(32 + cw)*8 + q)*512 + l8);
        wdreg[q] = *(const short8*)(Wswz + ((size_t)(64 + cw)*8 + q)*512 + l8);
    }
    float c[4], hm[4];
    #pragma unroll
    for (int i = 0; i < 4; ++i){ c[i] = 0.0f; hm[i] = -2.0f; }
    // zero buffer 1 (read at t=0), both halves of h and c
    for (int i = tid; i < HB; i += 512){ smem[HB + i] = 0; smem[3*HB + i] = 0; }
    // preload gq=3 tiles for my 8 waves into LDS (tiles 48+h*8..+8, 64 KB)
    {
        const int4* wsrc = (const int4*)(Wswz + (size_t)(48 + h*8)*4096);
        int4* wdst = (int4*)wlds;
        for (int i = tid; i < 4096; i += 512) wdst[i] = wsrc[i];
    }
    __syncthreads();

    const ushortT* xg_g  = xg   + (size_t)g*SEQ*16384 + ((size_t)(cw>>1)*64 + l)*32 + (cw&1)*16;
    const ushortT* tft_g = tftg + (size_t)g*SEQ*1024  + (size_t)l8;
    const ushortT* wl    = wlds + (size_t)w*4096 + l8;
    const f32x4 fz = {0.f,0.f,0.f,0.f};

    for (int t = 0; t < SEQ; ++t){
        int pb = t & 1, ab = 1 - pb;
        ushortT* hb = smem + (size_t)ab*HB;
        ushortT* cb = smem + 2*HB + (size_t)ab*HB;
        // per-step inputs, issued early (consumed in elementwise)
        short8 xA  = *(const short8*)(xg_g + (size_t)t*16384);
        short8 xB  = *(const short8*)(xg_g + (size_t)t*16384 + 8);
        short8 aT0 = *(const short8*)(tft_g + (size_t)t*1024);
        short8 aT1 = *(const short8*)(tft_g + (size_t)t*1024 + 512);

        f32x4 acc[5];
        #pragma unroll
        for (int i = 0; i < 5; ++i) acc[i] = fz;
        // ---- local K-half MFMA (my own columns; valid since end of previous step) ----
        #pragma unroll
        for (int qi = 0; qi < 4; ++qi){
            int q = qlo + qi;
            short8 a  = *(const short8*)(hb + lm*264 + q*32 + lq*8);
            short8 ca = *(const short8*)(cb + lm*264 + q*32 + lq*8);
            short8 b3 = *(const short8*)(wl + q*512);
            acc[0] = __builtin_amdgcn_mfma_f32_16x16x32_bf16(a,  wg0[q],   acc[0], 0, 0, 0);
            acc[1] = __builtin_amdgcn_mfma_f32_16x16x32_bf16(a,  wg1[q],   acc[1], 0, 0, 0);
            acc[2] = __builtin_amdgcn_mfma_f32_16x16x32_bf16(a,  wg2[q],   acc[2], 0, 0, 0);
            acc[3] = __builtin_amdgcn_mfma_f32_16x16x32_bf16(a,  b3,       acc[3], 0, 0, 0);
            acc[4] = __builtin_amdgcn_mfma_f32_16x16x32_bf16(ca, wdreg[q], acc[4], 0, 0, 0);
        }
        f32x4 acc_ts = fz;
        acc_ts = __builtin_amdgcn_mfma_f32_16x16x32_bf16(aT0, twf[0], acc_ts, 0, 0, 0);
        acc_ts = __builtin_amdgcn_mfma_f32_16x16x32_bf16(aT1, twf[1], acc_ts, 0, 0, 0);

        // ---- spin (tid0 only) + import partner slice; hidden under local MFMA ----
        if (t > 0){
            if (tid == 0){
                unsigned want = fb + (unsigned)t;
                for (int it = 0; it < 20000000; ++it){
                    if (__hip_atomic_load(&flags[(size_t)pblk*64],
                            __ATOMIC_ACQUIRE, __HIP_MEMORY_SCOPE_AGENT) >= want) break;
                    __builtin_amdgcn_s_sleep(2);
                }
            }
            __syncthreads();                            // partner data visible
            int part = tid >> 8, i = tid & 255, row = i >> 4, c16 = i & 15;
            const unsigned long long* src = (const unsigned long long*)(xbuf +
                ((((size_t)pblk*2 + ab)*2 + part)*16 + row)*128 + c16*8);
            unsigned long long u0 = __hip_atomic_load(src+0, __ATOMIC_RELAXED, __HIP_MEMORY_SCOPE_AGENT);
            unsigned long long u1 = __hip_atomic_load(src+1, __ATOMIC_RELAXED, __HIP_MEMORY_SCOPE_AGENT);
            ushortT* dst = (part ? cb : hb) + row*264 + (1-h)*128 + c16*8;
            union { int4 v; unsigned long long uu[2]; } u;
            u.uu[0] = u0; u.uu[1] = u1;
            *(int4*)dst = u.v;
            __syncthreads();                            // remote half complete in LDS
        }
        // ---- remote K-half MFMA ----
        #pragma unroll
        for (int qi = 0; qi < 4; ++qi){
            int q = qro + qi;
            short8 a  = *(const short8*)(hb + lm*264 + q*32 + lq*8);
            short8 ca = *(const short8*)(cb + lm*264 + q*32 + lq*8);
            short8 b3 = *(const short8*)(wl + q*512);
            acc[0] = __builtin_amdgcn_mfma_f32_16x16x32_bf16(a,  wg0[q],   acc[0], 0, 0, 0);
            acc[1] = __builtin_amdgcn_mfma_f32_16x16x32_bf16(a,  wg1[q],   acc[1], 0, 0, 0);
            acc[2] = __builtin_amdgcn_mfma_f32_16x16x32_bf16(a,  wg2[q],   acc[2], 0, 0, 0);
            acc[3] = __builtin_amdgcn_mfma_f32_16x16x32_bf16(a,  b3,       acc[3], 0, 0, 0);
            acc[4] = __builtin_amdgcn_mfma_f32_16x16x32_bf16(ca, wdreg[q], acc[4], 0, 0, 0);
        }

        ushortT* hbw = smem + (size_t)pb*HB;
        ushortT* cbw = smem + 2*HB + (size_t)pb*HB;
        #pragma unroll
        for (int r = 0; r < 4; ++r){
            float F   = acc[0][r] + b2f(((const ushortT*)&xA)[r]);
            float I   = acc[1][r] + b2f(((const ushortT*)&xA)[4+r]);
            float O   = acc[2][r] + b2f(((const ushortT*)&xB)[r]);
            float CT  = acc[3][r] + b2f(((const ushortT*)&xB)[4+r]);
            float cwd = acc[4][r] + wdb;
            float ts  = acc_ts[r] + tb;
            float cc  = c[r];
            float cs1 = tanh_fast(cwd);
            float cadj = cc - cs1 + cs1*ts;
            float cn  = sigm(F)*cadj + sigm(I)*sigm(CT);
            float hv  = sigm(O)*tanh_fast(cn);
            c[r]  = cn;
            hm[r] = fmaxf(hm[r], hv);
            hbw[(lq*4 + r)*264 + col] = f2b(hv);
            cbw[(lq*4 + r)*264 + col] = f2b(cn);
        }
        __syncthreads();                                // my LDS half complete
        if (t < SEQ-1){
            // export my h/c slice (8 KB) via coalesced int4 device-coherent stores
            int part = tid >> 8, i = tid & 255, row = i >> 4, c16 = i & 15;
            const ushortT* src = (part ? cbw : hbw) + row*264 + h*128 + c16*8;
            union { int4 v; unsigned long long uu[2]; } u; u.v = *(const int4*)src;
            unsigned long long* dst = (unsigned long long*)(xbuf +
                ((((size_t)blk*2 + pb)*2 + part)*16 + row)*128 + c16*8);
            __hip_atomic_store(dst+0, u.uu[0], __ATOMIC_RELAXED, __HIP_MEMORY_SCOPE_AGENT);
            __hip_atomic_store(dst+1, u.uu[1], __ATOMIC_RELAXED, __HIP_MEMORY_SCOPE_AGENT);
            __syncthreads();                            // all export stores drained
            if (tid == 0)
                __hip_atomic_store(&flags[(size_t)blk*64], fb + (unsigned)t + 1u,
                                   __ATOMIC_RELEASE, __HIP_MEMORY_SCOPE_AGENT);
        }
        // hs write after the flag: off the partner's critical path
        if (write_hs && tid < 256){
            int row = tid >> 4, c16 = tid & 15;
            int4 v = *(const int4*)(hbw + row*264 + h*128 + c16*8);
            *(int4*)(hs + ((size_t)(g*16 + row)*SEQ + t)*256 + h*128 + c16*8) = v;
        }
    }
    #pragma unroll
    for (int r = 0; r < 4; ++r)
        maxh[(size_t)(g*16 + lq*4 + r)*256 + col] = hm[r];
}

// ---- snapshot e_k = x[:,0,:] (bf16) ----
__global__ void k_ekcopy(const ushortT* __restrict__ x, ushortT* __restrict__ ek){
    int b = blockIdx.x, l = threadIdx.x;   // 64 threads, 4 ushorts each
    ((int2*)(ek + (size_t)b*256))[l] = ((const int2*)(x + (size_t)b*SEQ*256))[l];
}

// ---- e_k @ w1[0:256] + w1_b (f32 weights) ----
__global__ void k_ekw(const ushortT* __restrict__ ek, const float* __restrict__ w1w,
                      const float* __restrict__ w1b, float* __restrict__ ekw){
    int b = blockIdx.x, l = threadIdx.x;
    float acc = w1b[l];
    const ushortT* e = ek + (size_t)b*256;
    for (int d = 0; d < 256; ++d)
        acc += b2f(e[d]) * w1w[(size_t)d*64 + l];
    ekw[b*64 + l] = acc;
}

// ---- attention + aligned + gen_x, one wave per (b, s') ----
__global__ __launch_bounds__(512) void k_attn(const ushortT* __restrict__ ekbuf,
        const ushortT* __restrict__ whk, const float* __restrict__ ekw,
        const float* __restrict__ w1w, const float* __restrict__ w2w,
        const float* __restrict__ w2b, const float* __restrict__ nn,
        const float* __restrict__ pn, ushortT* __restrict__ genx){
    int w = threadIdx.x >> 6, l = threadIdx.x & 63;
    int wid = blockIdx.x*8 + w;
    int b = wid / SEQ, sp = wid % SEQ;
    const ushortT* ek = ekbuf + (size_t)b*256;
    const ushortT* wr = whk + ((size_t)b*SEQ + (sp > 0 ? sp-1 : 0))*256;
    size_t orow = ((size_t)b*SEQ + sp)*256;
    float a0, a1;
    if (sp == 0){ a0 = 1.0f; a1 = 0.0f; }
    else {
        float acc = ekw[b*64 + l];
        for (int d = 0; d < 256; ++d)
            acc += b2f(wr[d]) * w1w[(size_t)(256 + d)*64 + l];
        float u  = tanh_fast(acc);
        float p0 = u * w2w[l*2 + 0];
        float p1 = u * w2w[l*2 + 1];
        #pragma unroll
        for (int off = 32; off >= 1; off >>= 1){
            p0 += __shfl_xor(p0, off, 64);
            p1 += __shfl_xor(p1, off, 64);
        }
        float v0 = p0 + w2b[0], v1 = p1 + w2b[1];
        a0 = sigm(v0 - v1); a1 = 1.0f - a0;
    }
    #pragma unroll
    for (int i = 0; i < 4; ++i){
        int d = i*64 + l;
        float al = b2f(ek[d])*a0 + b2f(wr[d])*a1;
        float gv = al + nn[orow + d] - pn[orow + d];
        genx[orow + d] = f2b(gv);
    }
}

// ---- heads: out = maxh @ out_w + out_b (all f32) ----
__global__ void k_final(const float* __restrict__ mh1, const float* __restrict__ mh2,
                        const float* __restrict__ ow, const float* __restrict__ ob,
                        float* __restrict__ outp){
    int th = threadIdx.x;
    const float* mh = blockIdx.x ? mh2 : mh1;
    int b = th >> 1, cc = th & 1;
    float acc = ob[cc];
    for (int d = 0; d < 256; ++d)
        acc += mh[b*256 + d] * ow[d*2 + cc];
    outp[blockIdx.x*512 + th] = acc;
}

extern "C" void kernel_launch(void* const* d_in, const int* in_sizes, int n_in,
                              void* d_out, int out_size, void* d_ws, size_t ws_size,
                              hipStream_t stream) {
    const float* input_seqs = (const float*)d_in[0];
    const float* seq_time   = (const float*)d_in[3];
    const float* nn     = (const float*)d_in[6];
    const float* pn     = (const float*)d_in[7];
    const float* emb2_w = (const float*)d_in[9];
    const float* emb2_b = (const float*)d_in[10];
    const float* Wall_w = (const float*)d_in[11];
    const float* Wall_b = (const float*)d_in[12];
    const float* Uall_w = (const float*)d_in[13];
    const float* Uall_b = (const float*)d_in[14];
    const float* Wd_w   = (const float*)d_in[15];
    const float* Wd_b   = (const float*)d_in[16];
    const float* time_w = (const float*)d_in[17];
    const float* time_b = (const float*)d_in[18];
    const float* sel_w  = (const float*)d_in[19];
    const float* sel_b  = (const float*)d_in[20];
    const float* whk_w  = (const float*)d_in[21];
    const float* whk_b  = (const float*)d_in[22];
    const float* w1_w   = (const float*)d_in[23];
    const float* w1_b   = (const float*)d_in[24];
    const float* w2_w   = (const float*)d_in[25];
    const float* w2_b   = (const float*)d_in[26];
    const float* out_w  = (const float*)d_in[27];
    const float* out_b  = (const float*)d_in[28];

    const size_t NSZ = (size_t)in_sizes[6];   // B*SEQ*D noise element count

    // allow >64KB dynamic LDS for k_scan (160 KB/CU on gfx950)
    static bool attr_done = false;
    if (!attr_done){
        hipFuncSetAttribute((const void*)k_scan,
                            hipFuncAttributeMaxDynamicSharedMemorySize, 160*1024);
        attr_done = true;
    }
    const size_t SCAN_LDS = (size_t)(4*HB + 8*4096) * sizeof(ushortT);  // 99,328 B

    char* wsb = (char*)d_ws;
    size_t off = 0;
    auto alloc = [&](size_t bytes){ void* p = wsb + off; off += (bytes + 255) & ~(size_t)255; return p; };
    ushortT* Wswz  = (ushortT*)alloc(80u*8*512*2);     // Wall tiles 0..63, Wd tiles 64..79
    ushortT* Uswz  = (ushortT*)alloc(64u*8*512*2);
    ushortT* Eswz  = (ushortT*)alloc(16u*8*512*2);
    ushortT* Hswz  = (ushortT*)alloc(16u*8*512*2);
    ushortT* TWswz = (ushortT*)alloc(16u*8*512*2);     // time_w (only q=0,1 slots used)
    ushortT* TFT   = (ushortT*)alloc((size_t)16*SEQ*1024*2);   // 6.6 MB
    ushortT* X     = (ushortT*)alloc((size_t)NB*SEQ*256*2);    // 26.2 MB (reused as GENX)
    ushortT* XG    = (ushortT*)alloc((size_t)16*SEQ*16384*2);  // 100 MB
    ushortT* HS    = (ushortT*)alloc((size_t)NB*SEQ*256*2);    // 26.2 MB (also input bf16 staging)
    ushortT* EK    = (ushortT*)alloc((size_t)NB*256*2);
    float*  MAXH1  = (float*)alloc((size_t)NB*256*4);
    float*  MAXH2  = (float*)alloc((size_t)NB*256*4);
    float*  EKW    = (float*)alloc((size_t)NB*64*4);
    ushortT* XBUF  = (ushortT*)alloc((size_t)32*2*2*16*128*2); // 512 KB pair-exchange
    unsigned* FLAGS= (unsigned*)alloc((size_t)32*64*4);        // 8 KB, 256B-strided flags

    float* outp = (float*)d_out;
    // outputs 2,3 are pass-throughs (predicted_noise, normal_noise), f32
    hipMemcpyAsync(outp + 1024,       pn, NSZ*4, hipMemcpyDeviceToDevice, stream);
    hipMemcpyAsync(outp + 1024 + NSZ, nn, NSZ*4, hipMemcpyDeviceToDevice, stream);

    k_zeroflags<<<8, 256, 0, stream>>>(FLAGS);
    k_swizzle<<<dim3(64,8), 64, 0, stream>>>(Wall_w, 1024, Wswz, 0);
    k_swizzle<<<dim3(16,8), 64, 0, stream>>>(Wd_w,    256, Wswz, 64);
    k_swizzle<<<dim3(64,8), 64, 0, stream>>>(Uall_w, 1024, Uswz, 0);
    k_swizzle<<<dim3(16,8), 64, 0, stream>>>(emb2_w,  256, Eswz, 0);
    k_swizzle<<<dim3(16,8), 64, 0, stream>>>(whk_w,   256, Hswz, 0);
    k_swizzle<<<dim3(16,2), 64, 0, stream>>>(time_w,  256, TWswz, 0);  // K=64 → q<2

    k_tft<<<3200, 64, 0, stream>>>(seq_time, sel_w, sel_b, TFT);
    k_cvt<<<12800, 256, 0, stream>>>(input_seqs, HS);          // f32 input → bf16 (staged in HS)
    k_gemm256<<<3200, 512, 0, stream>>>(HS, Eswz, emb2_b, X);
    k_ekcopy<<<256, 64, 0, stream>>>(X, EK);
    k_ekw<<<256, 64, 0, stream>>>(EK, w1_w, w1_b, EKW);
    k_gemmgates<<<3200, 512, 0, stream>>>(X, Uswz, Wall_b, Uall_b, XG);
    k_scan<<<32, 512, SCAN_LDS, stream>>>(XG, TFT, Wswz, TWswz, Wd_b, time_b, HS, MAXH1, 1,
                                          XBUF, FLAGS, 0u);
    k_gemm256<<<3200, 512, 0, stream>>>(HS, Hswz, whk_b, HS);   // whk in-place (block-local rows)
    k_attn<<<6400, 512, 0, stream>>>(EK, HS, EKW, w1_w, w2_w, w2_b, nn, pn, X);  // genx → X region
    k_gemmgates<<<3200, 512, 0, stream>>>(X, Uswz, Wall_b, Uall_b, XG);
    k_scan<<<32, 512, SCAN_LDS, stream>>>(XG, TFT, Wswz, TWswz, Wd_b, time_b, HS, MAXH2, 0,
                                          XBUF, FLAGS, (unsigned)SEQ);
    k_final<<<2, 512, 0, stream>>>(MAXH1, MAXH2, out_w, out_b, outp);
}

// Round 6
// 2115.966 us; speedup vs baseline: 1.7272x; 1.5156x over previous
//
#include <hip/hip_runtime.h>
#include <hip/hip_bf16.h>
#include <cstdint>

typedef __attribute__((ext_vector_type(8))) short short8;
typedef __attribute__((ext_vector_type(4))) float f32x4;
typedef unsigned short ushortT;

#define SEQ 200
#define NB  256

__device__ __forceinline__ float b2f(ushortT u){
    union { unsigned u; float f; } v; v.u = ((unsigned)u) << 16; return v.f;
}
__device__ __forceinline__ ushortT f2b(float f){
    union { float f; unsigned u; } v; v.f = f;
    unsigned r = v.u + 0x7FFFu + ((v.u >> 16) & 1u);
    return (ushortT)(r >> 16);
}
// fast reciprocal: ~1 ulp, far below bf16 rounding; avoids the full div sequence
__device__ __forceinline__ float frcp(float x){
    float r; asm("v_rcp_f32 %0, %1" : "=v"(r) : "v"(x)); return r;
}
__device__ __forceinline__ float sigm(float x){ return frcp(1.0f + __expf(-x)); }
__device__ __forceinline__ float tanh_fast(float x){
    float ax = fabsf(x);
    float t = __expf(-2.0f * ax);
    float r = (1.0f - t) * frcp(1.0f + t);
    return copysignf(r, x);
}

// ---- f32 -> bf16 bulk convert (n multiple of 1024) ----
__global__ void k_cvt(const float* __restrict__ in, ushortT* __restrict__ out){
    size_t i = ((size_t)blockIdx.x*256 + threadIdx.x)*4;
    float4 v = *(const float4*)(in + i);
    ushortT o[4] = { f2b(v.x), f2b(v.y), f2b(v.z), f2b(v.w) };
    *(int2*)(out + i) = *(int2*)o;
}

// ---- swizzle a (K x ncols) f32 row-major matrix into bf16 MFMA B-fragment tiles ----
// tile T (16 cols), kstep q (32 k): lane l holds B[k = q*32+(l>>4)*8+j][n = T*16+(l&15)], j=0..7
__global__ void k_swizzle(const float* __restrict__ src, int ncols,
                          ushortT* __restrict__ dst, int tile0){
    int Tl = blockIdx.x, q = blockIdx.y, l = threadIdx.x;
    int n  = Tl*16 + (l & 15);
    int kb = q*32 + (l >> 4)*8;
    short8 v;
    #pragma unroll
    for (int j = 0; j < 8; ++j) ((ushortT*)&v)[j] = f2b(src[(size_t)(kb + j)*ncols + n]);
    *(short8*)(dst + ((size_t)(tile0 + Tl)*8 + q)*512 + (size_t)l*8) = v;
}

// ---- tft = 1 - tanh((t/180*selw+selb)^2), stored as scan A-fragments (bf16) ----
__global__ void k_tft(const float* __restrict__ sts, const float* __restrict__ selw,
                      const float* __restrict__ selb, ushortT* __restrict__ tft){
    int l = threadIdx.x, g = blockIdx.x / SEQ, t = blockIdx.x % SEQ;
    int lm = l & 15, lq = l >> 4;
    float tv = sts[(size_t)(g*16 + lm)*SEQ + t] * (1.0f/180.0f);
    size_t base = (size_t)(g*SEQ + t)*1024 + (size_t)l*8;
    #pragma unroll
    for (int q = 0; q < 2; ++q){
        short8 v;
        #pragma unroll
        for (int j = 0; j < 8; ++j){
            int u = q*32 + lq*8 + j;
            float a = tv * selw[u] + selb[u];
            ((ushortT*)&v)[j] = f2b(1.0f - tanh_fast(a*a));
        }
        *(short8*)(tft + base + (size_t)q*512) = v;
    }
}

// ---- generic C[rows x 256] = A[rows x 256] @ Bswz(16 tiles) + bias(f32), bf16 out ----
__global__ __launch_bounds__(512) void k_gemm256(const ushortT* A,
        const ushortT* __restrict__ Bswz, const float* __restrict__ bias, ushortT* out){
    __shared__ ushortT stage[16*256];
    int tid = threadIdx.x, w = tid >> 6, l = tid & 63, lm = l & 15, lq = l >> 4;
    size_t r0 = (size_t)blockIdx.x * 16;
    const f32x4 fz = {0.f,0.f,0.f,0.f};
    f32x4 acc[2] = {fz, fz};
    for (int q = 0; q < 8; ++q){
        short8 a = *(const short8*)(A + (r0 + lm)*256 + q*32 + lq*8);
        #pragma unroll
        for (int p = 0; p < 2; ++p){
            int T = 2*w + p;
            short8 b = *(const short8*)(Bswz + ((size_t)T*8 + q)*512 + (size_t)l*8);
            acc[p] = __builtin_amdgcn_mfma_f32_16x16x32_bf16(a, b, acc[p], 0, 0, 0);
        }
    }
    #pragma unroll
    for (int p = 0; p < 2; ++p){
        int n = (2*w + p)*16 + lm;
        float bs = bias[n];
        #pragma unroll
        for (int r = 0; r < 4; ++r)
            stage[(lq*4 + r)*256 + n] = f2b(acc[p][r] + bs);
    }
    __syncthreads();
    int row = tid >> 5, c8 = tid & 31;
    int4 v = *(const int4*)(stage + row*256 + c8*8);
    *(int4*)(out + (r0 + row)*256 + (size_t)c8*8) = v;
}

// ---- W1P[rows x 64] = A[rows x 256] @ W1swz(4 tiles), f32 out (no bias) ----
__global__ __launch_bounds__(256) void k_gemm64(const ushortT* __restrict__ A,
        const ushortT* __restrict__ Bswz, float* __restrict__ out){
    int tid = threadIdx.x, w = tid >> 6, l = tid & 63, lm = l & 15, lq = l >> 4;
    size_t r0 = (size_t)blockIdx.x * 16;
    const f32x4 fz = {0.f,0.f,0.f,0.f};
    f32x4 acc = fz;
    for (int q = 0; q < 8; ++q){
        short8 a = *(const short8*)(A + (r0 + lm)*256 + q*32 + lq*8);
        short8 b = *(const short8*)(Bswz + ((size_t)w*8 + q)*512 + (size_t)l*8);
        acc = __builtin_amdgcn_mfma_f32_16x16x32_bf16(a, b, acc, 0, 0, 0);
    }
    #pragma unroll
    for (int r = 0; r < 4; ++r)
        out[(r0 + lq*4 + r)*64 + w*16 + lm] = acc[r];
}

// ---- gates pre-act: xg = A@Uall + (Wall_b+Uall_b), written in scan per-lane order ----
__global__ __launch_bounds__(512) void k_gemmgates(const ushortT* __restrict__ A,
        const ushortT* __restrict__ Bswz, const float* __restrict__ bW,
        const float* __restrict__ bU, ushortT* __restrict__ out){
    int tid = threadIdx.x, w = tid >> 6, l = tid & 63, lm = l & 15, lq = l >> 4;
    int g = blockIdx.x / SEQ, t = blockIdx.x % SEQ;
    const f32x4 fz = {0.f,0.f,0.f,0.f};
    f32x4 acc[8] = {fz,fz,fz,fz,fz,fz,fz,fz};
    const ushortT* Arow = A + ((size_t)(g*16 + lm)*SEQ + t)*256;
    for (int q = 0; q < 8; ++q){
        short8 a = *(const short8*)(Arow + q*32 + lq*8);
        #pragma unroll
        for (int gq = 0; gq < 4; ++gq)
        #pragma unroll
        for (int p = 0; p < 2; ++p){
            int T = gq*16 + 2*w + p;
            short8 b = *(const short8*)(Bswz + ((size_t)T*8 + q)*512 + (size_t)l*8);
            acc[gq*2+p] = __builtin_amdgcn_mfma_f32_16x16x32_bf16(a, b, acc[gq*2+p], 0, 0, 0);
        }
    }
    short8 ch[4];
    #pragma unroll
    for (int gq = 0; gq < 4; ++gq)
    #pragma unroll
    for (int p = 0; p < 2; ++p){
        int n = gq*256 + w*32 + p*16 + lm;
        float bs = bW[n] + bU[n];
        #pragma unroll
        for (int r = 0; r < 4; ++r)
            ((ushortT*)&ch[p*2 + (gq>>1)])[(gq&1)*4 + r] = f2b(acc[gq*2+p][r] + bs);
    }
    size_t base = (size_t)(g*SEQ + t)*16384 + (size_t)(w*64 + l)*32;
    #pragma unroll
    for (int ci = 0; ci < 4; ++ci) *(short8*)(out + base + ci*8) = ch[ci];
}

// ---- zero the exchange flags (fresh per launch) ----
__global__ void k_zeroflags(unsigned* __restrict__ f){
    f[blockIdx.x*256 + threadIdx.x] = 0;
}

// ---- persistent TLSTM scan: 32 WGs (2 per batch-group), 512 threads / 8 waves each ----
// R3-proven schedule: full 8-q MFMA block uninterrupted; exchange (export -> flag ->
// spin -> import) at end of step. Weights fully resident (gq0,1,2+Wd in regs, gq3 LDS).
// Delta vs R3: hs global write overlaps the tid0 spin (threads 256-511).
#define HB (16*264)
__global__ __launch_bounds__(512, 2) void k_scan(const ushortT* __restrict__ xg,
        const ushortT* __restrict__ tftg, const ushortT* __restrict__ Wswz,
        const ushortT* __restrict__ twswz, const float* __restrict__ wdb_g,
        const float* __restrict__ timeb, ushortT* __restrict__ hs,
        float* __restrict__ maxh, int write_hs,
        ushortT* __restrict__ xbuf, unsigned* __restrict__ flags, unsigned fb){
    extern __shared__ ushortT smem[];
    // layout: hbuf[2] = smem[0..2*HB), cbuf[2] = smem[2*HB..4*HB), wlds = smem[4*HB..)
    ushortT* wlds = smem + 4*HB;
    int tid = threadIdx.x, w = tid >> 6, l = tid & 63, lm = l & 15, lq = l >> 4;
    int blk = blockIdx.x;
    int h = blk >> 4, g = blk & 15;
    int pblk = (1 - h)*16 + g;           // partner block
    int cw = h*8 + w;                    // global 16-col tile index 0..15
    int col = cw*16 + lm;
    int l8 = l*8;
    float wdb = wdb_g[col];
    float tb  = timeb[col];
    short8 twf[2];
    #pragma unroll
    for (int q2 = 0; q2 < 2; ++q2)
        twf[q2] = *(const short8*)(twswz + ((size_t)cw*8 + q2)*512 + l8);
    // resident weight tiles: gates gq=0,1,2 and Wd in registers (AGPR-eligible)
    short8 wg0[8], wg1[8], wg2[8], wdreg[8];
    #pragma unroll
    for (int q = 0; q < 8; ++q){
        wg0[q]   = *(const short8*)(Wswz + ((size_t)( 0 + cw)*8 + q)*512 + l8);
        wg1[q]   = *(const short8*)(Wswz + ((size_t)(16 + cw)*8 + q)*512 + l8);
        wg2[q]   = *(const short8*)(Wswz + ((size_t)(32 + cw)*8 + q)*512 + l8);
        wdreg[q] = *(const short8*)(Wswz + ((size_t)(64 + cw)*8 + q)*512 + l8);
    }
    float c[4], hm[4];
    #pragma unroll
    for (int i = 0; i < 4; ++i){ c[i] = 0.0f; hm[i] = -2.0f; }
    // zero buffer 1 (read at t=0), both halves of h and c
    for (int i = tid; i < HB; i += 512){ smem[HB + i] = 0; smem[3*HB + i] = 0; }
    // preload gq=3 tiles for my 8 waves into LDS (tiles 48+h*8..+8, 64 KB)
    {
        const int4* wsrc = (const int4*)(Wswz + (size_t)(48 + h*8)*4096);
        int4* wdst = (int4*)wlds;
        for (int i = tid; i < 4096; i += 512) wdst[i] = wsrc[i];
    }
    __syncthreads();

    const ushortT* xg_g  = xg   + (size_t)g*SEQ*16384 + ((size_t)(cw>>1)*64 + l)*32 + (cw&1)*16;
    const ushortT* tft_g = tftg + (size_t)g*SEQ*1024  + (size_t)l8;
    const ushortT* wl    = wlds + (size_t)w*4096 + l8;
    const f32x4 fz = {0.f,0.f,0.f,0.f};

    for (int t = 0; t < SEQ; ++t){
        int pb = t & 1, ab = 1 - pb;
        const ushortT* hb = smem + (size_t)ab*HB;
        const ushortT* cb = smem + 2*HB + (size_t)ab*HB;
        // per-step inputs, issued early (consumed in elementwise)
        short8 xA  = *(const short8*)(xg_g + (size_t)t*16384);
        short8 xB  = *(const short8*)(xg_g + (size_t)t*16384 + 8);
        short8 aT0 = *(const short8*)(tft_g + (size_t)t*1024);
        short8 aT1 = *(const short8*)(tft_g + (size_t)t*1024 + 512);

        f32x4 acc[5];
        #pragma unroll
        for (int i = 0; i < 5; ++i) acc[i] = fz;
        #pragma unroll
        for (int q = 0; q < 8; ++q){
            short8 a  = *(const short8*)(hb + lm*264 + q*32 + lq*8);
            short8 ca = *(const short8*)(cb + lm*264 + q*32 + lq*8);
            short8 b3 = *(const short8*)(wl + q*512);
            acc[0] = __builtin_amdgcn_mfma_f32_16x16x32_bf16(a,  wg0[q],   acc[0], 0, 0, 0);
            acc[1] = __builtin_amdgcn_mfma_f32_16x16x32_bf16(a,  wg1[q],   acc[1], 0, 0, 0);
            acc[2] = __builtin_amdgcn_mfma_f32_16x16x32_bf16(a,  wg2[q],   acc[2], 0, 0, 0);
            acc[3] = __builtin_amdgcn_mfma_f32_16x16x32_bf16(a,  b3,       acc[3], 0, 0, 0);
            acc[4] = __builtin_amdgcn_mfma_f32_16x16x32_bf16(ca, wdreg[q], acc[4], 0, 0, 0);
        }
        f32x4 acc_ts = fz;
        acc_ts = __builtin_amdgcn_mfma_f32_16x16x32_bf16(aT0, twf[0], acc_ts, 0, 0, 0);
        acc_ts = __builtin_amdgcn_mfma_f32_16x16x32_bf16(aT1, twf[1], acc_ts, 0, 0, 0);

        ushortT* hbw = smem + (size_t)pb*HB;
        ushortT* cbw = smem + 2*HB + (size_t)pb*HB;
        #pragma unroll
        for (int r = 0; r < 4; ++r){
            float F   = acc[0][r] + b2f(((const ushortT*)&xA)[r]);
            float I   = acc[1][r] + b2f(((const ushortT*)&xA)[4+r]);
            float O   = acc[2][r] + b2f(((const ushortT*)&xB)[r]);
            float CT  = acc[3][r] + b2f(((const ushortT*)&xB)[4+r]);
            float cwd = acc[4][r] + wdb;
            float ts  = acc_ts[r] + tb;
            float cc  = c[r];
            float cs1 = tanh_fast(cwd);
            float cadj = cc - cs1 + cs1*ts;
            float cn  = sigm(F)*cadj + sigm(I)*sigm(CT);
            float hv  = sigm(O)*tanh_fast(cn);
            c[r]  = cn;
            hm[r] = fmaxf(hm[r], hv);
            hbw[(lq*4 + r)*264 + col] = f2b(hv);
            cbw[(lq*4 + r)*264 + col] = f2b(cn);
        }
        __syncthreads();                                   // my LDS half complete
        if (t < SEQ-1){
            // export my h/c slice (8 KB) via coalesced int4 device-coherent stores
            {
                int part = tid >> 8, i = tid & 255, row = i >> 4, c16 = i & 15;
                const ushortT* src = (part ? cbw : hbw) + row*264 + h*128 + c16*8;
                union { int4 v; unsigned long long uu[2]; } u; u.v = *(const int4*)src;
                unsigned long long* dst = (unsigned long long*)(xbuf +
                    ((((size_t)blk*2 + pb)*2 + part)*16 + row)*128 + c16*8);
                __hip_atomic_store(dst+0, u.uu[0], __ATOMIC_RELAXED, __HIP_MEMORY_SCOPE_AGENT);
                __hip_atomic_store(dst+1, u.uu[1], __ATOMIC_RELAXED, __HIP_MEMORY_SCOPE_AGENT);
            }
            __syncthreads();                               // all export stores drained
            if (tid == 0){
                __hip_atomic_store(&flags[(size_t)blk*64], fb + (unsigned)t + 1u,
                                   __ATOMIC_RELEASE, __HIP_MEMORY_SCOPE_AGENT);
                unsigned want = fb + (unsigned)t + 1u;
                for (int it = 0; it < 20000000; ++it){
                    if (__hip_atomic_load(&flags[(size_t)pblk*64],
                            __ATOMIC_ACQUIRE, __HIP_MEMORY_SCOPE_AGENT) >= want) break;
                    __builtin_amdgcn_s_sleep(2);
                }
            }
            // hs write overlaps the spin (threads 256-511, reading completed hbw)
            if (write_hs && tid >= 256){
                int i = tid - 256, row = i >> 4, c16 = i & 15;
                int4 v = *(const int4*)(hbw + row*264 + h*128 + c16*8);
                *(int4*)(hs + ((size_t)(g*16 + row)*SEQ + t)*256 + h*128 + c16*8) = v;
            }
            __syncthreads();                               // partner data visible
            // import partner half -> LDS (write buffer of this step = read buf of next)
            {
                int part = tid >> 8, i = tid & 255, row = i >> 4, c16 = i & 15;
                const unsigned long long* src = (const unsigned long long*)(xbuf +
                    ((((size_t)pblk*2 + pb)*2 + part)*16 + row)*128 + c16*8);
                unsigned long long u0 = __hip_atomic_load(src+0, __ATOMIC_RELAXED, __HIP_MEMORY_SCOPE_AGENT);
                unsigned long long u1 = __hip_atomic_load(src+1, __ATOMIC_RELAXED, __HIP_MEMORY_SCOPE_AGENT);
                ushortT* dst = (part ? cbw : hbw) + row*264 + (1-h)*128 + c16*8;
                union { int4 v; unsigned long long uu[2]; } u;
                u.uu[0] = u0; u.uu[1] = u1;
                *(int4*)dst = u.v;
            }
            __syncthreads();                               // buf[pb] complete for next step
        } else {
            if (write_hs && tid < 256){
                int row = tid >> 4, c16 = tid & 15;
                int4 v = *(const int4*)(hbw + row*264 + h*128 + c16*8);
                *(int4*)(hs + ((size_t)(g*16 + row)*SEQ + t)*256 + h*128 + c16*8) = v;
            }
        }
    }
    #pragma unroll
    for (int r = 0; r < 4; ++r)
        maxh[(size_t)(g*16 + lq*4 + r)*256 + col] = hm[r];
}

// ---- snapshot e_k = x[:,0,:] (bf16) ----
__global__ void k_ekcopy(const ushortT* __restrict__ x, ushortT* __restrict__ ek){
    int b = blockIdx.x, l = threadIdx.x;   // 64 threads, 4 ushorts each
    ((int2*)(ek + (size_t)b*256))[l] = ((const int2*)(x + (size_t)b*SEQ*256))[l];
}

// ---- e_k @ w1[0:256] + w1_b (f32 weights) ----
__global__ void k_ekw(const ushortT* __restrict__ ek, const float* __restrict__ w1w,
                      const float* __restrict__ w1b, float* __restrict__ ekw){
    int b = blockIdx.x, l = threadIdx.x;
    float acc = w1b[l];
    const ushortT* e = ek + (size_t)b*256;
    for (int d = 0; d < 256; ++d)
        acc += b2f(e[d]) * w1w[(size_t)d*64 + l];
    ekw[b*64 + l] = acc;
}

// ---- attention + aligned + gen_x, one wave per (b, s'); w1-part precomputed in W1P ----
__global__ __launch_bounds__(512) void k_attn(const ushortT* __restrict__ ekbuf,
        const ushortT* __restrict__ whk, const float* __restrict__ ekw,
        const float* __restrict__ w1p, const float* __restrict__ w2w,
        const float* __restrict__ w2b, const float* __restrict__ nn,
        const float* __restrict__ pn, ushortT* __restrict__ genx){
    int w = threadIdx.x >> 6, l = threadIdx.x & 63;
    int wid = blockIdx.x*8 + w;
    int b = wid / SEQ, sp = wid % SEQ;
    const ushortT* ek = ekbuf + (size_t)b*256;
    const ushortT* wr = whk + ((size_t)b*SEQ + (sp > 0 ? sp-1 : 0))*256;
    size_t orow = ((size_t)b*SEQ + sp)*256;
    float a0, a1;
    if (sp == 0){ a0 = 1.0f; a1 = 0.0f; }
    else {
        float acc = ekw[b*64 + l] + w1p[((size_t)b*SEQ + sp-1)*64 + l];
        float u  = tanh_fast(acc);
        float p0 = u * w2w[l*2 + 0];
        float p1 = u * w2w[l*2 + 1];
        #pragma unroll
        for (int off = 32; off >= 1; off >>= 1){
            p0 += __shfl_xor(p0, off, 64);
            p1 += __shfl_xor(p1, off, 64);
        }
        float v0 = p0 + w2b[0], v1 = p1 + w2b[1];
        a0 = sigm(v0 - v1); a1 = 1.0f - a0;
    }
    #pragma unroll
    for (int i = 0; i < 4; ++i){
        int d = i*64 + l;
        float al = b2f(ek[d])*a0 + b2f(wr[d])*a1;
        float gv = al + nn[orow + d] - pn[orow + d];
        genx[orow + d] = f2b(gv);
    }
}

// ---- heads: out = maxh @ out_w + out_b (all f32) ----
__global__ void k_final(const float* __restrict__ mh1, const float* __restrict__ mh2,
                        const float* __restrict__ ow, const float* __restrict__ ob,
                        float* __restrict__ outp){
    int th = threadIdx.x;
    const float* mh = blockIdx.x ? mh2 : mh1;
    int b = th >> 1, cc = th & 1;
    float acc = ob[cc];
    for (int d = 0; d < 256; ++d)
        acc += mh[b*256 + d] * ow[d*2 + cc];
    outp[blockIdx.x*512 + th] = acc;
}

extern "C" void kernel_launch(void* const* d_in, const int* in_sizes, int n_in,
                              void* d_out, int out_size, void* d_ws, size_t ws_size,
                              hipStream_t stream) {
    const float* input_seqs = (const float*)d_in[0];
    const float* seq_time   = (const float*)d_in[3];
    const float* nn     = (const float*)d_in[6];
    const float* pn     = (const float*)d_in[7];
    const float* emb2_w = (const float*)d_in[9];
    const float* emb2_b = (const float*)d_in[10];
    const float* Wall_w = (const float*)d_in[11];
    const float* Wall_b = (const float*)d_in[12];
    const float* Uall_w = (const float*)d_in[13];
    const float* Uall_b = (const float*)d_in[14];
    const float* Wd_w   = (const float*)d_in[15];
    const float* Wd_b   = (const float*)d_in[16];
    const float* time_w = (const float*)d_in[17];
    const float* time_b = (const float*)d_in[18];
    const float* sel_w  = (const float*)d_in[19];
    const float* sel_b  = (const float*)d_in[20];
    const float* whk_w  = (const float*)d_in[21];
    const float* whk_b  = (const float*)d_in[22];
    const float* w1_w   = (const float*)d_in[23];
    const float* w1_b   = (const float*)d_in[24];
    const float* w2_w   = (const float*)d_in[25];
    const float* w2_b   = (const float*)d_in[26];
    const float* out_w  = (const float*)d_in[27];
    const float* out_b  = (const float*)d_in[28];

    const size_t NSZ = (size_t)in_sizes[6];   // B*SEQ*D noise element count

    // allow >64KB dynamic LDS for k_scan (160 KB/CU on gfx950)
    static bool attr_done = false;
    if (!attr_done){
        hipFuncSetAttribute((const void*)k_scan,
                            hipFuncAttributeMaxDynamicSharedMemorySize, 160*1024);
        attr_done = true;
    }
    const size_t SCAN_LDS = (size_t)(4*HB + 8*4096) * sizeof(ushortT);  // 99,328 B

    char* wsb = (char*)d_ws;
    size_t off = 0;
    auto alloc = [&](size_t bytes){ void* p = wsb + off; off += (bytes + 255) & ~(size_t)255; return p; };
    ushortT* Wswz  = (ushortT*)alloc(80u*8*512*2);     // Wall tiles 0..63, Wd tiles 64..79
    ushortT* Uswz  = (ushortT*)alloc(64u*8*512*2);
    ushortT* Eswz  = (ushortT*)alloc(16u*8*512*2);
    ushortT* Hswz  = (ushortT*)alloc(16u*8*512*2);
    ushortT* TWswz = (ushortT*)alloc(16u*8*512*2);     // time_w (only q=0,1 slots used)
    ushortT* W1swz = (ushortT*)alloc(4u*8*512*2);      // w1_w rows 256..511 (4 tiles)
    ushortT* TFT   = (ushortT*)alloc((size_t)16*SEQ*1024*2);   // 6.6 MB
    ushortT* X     = (ushortT*)alloc((size_t)NB*SEQ*256*2);    // 26.2 MB (reused as GENX)
    ushortT* XG    = (ushortT*)alloc((size_t)16*SEQ*16384*2);  // 100 MB
    ushortT* HS    = (ushortT*)alloc((size_t)NB*SEQ*256*2);    // 26.2 MB (also input bf16 staging)
    ushortT* EK    = (ushortT*)alloc((size_t)NB*256*2);
    float*  MAXH1  = (float*)alloc((size_t)NB*256*4);
    float*  MAXH2  = (float*)alloc((size_t)NB*256*4);
    float*  EKW    = (float*)alloc((size_t)NB*64*4);
    float*  W1P    = (float*)alloc((size_t)NB*SEQ*64*4);       // 13.1 MB
    ushortT* XBUF  = (ushortT*)alloc((size_t)32*2*2*16*128*2); // 512 KB pair-exchange
    unsigned* FLAGS= (unsigned*)alloc((size_t)32*64*4);        // 8 KB, 256B-strided flags

    float* outp = (float*)d_out;
    // outputs 2,3 are pass-throughs (predicted_noise, normal_noise), f32
    hipMemcpyAsync(outp + 1024,       pn, NSZ*4, hipMemcpyDeviceToDevice, stream);
    hipMemcpyAsync(outp + 1024 + NSZ, nn, NSZ*4, hipMemcpyDeviceToDevice, stream);

    k_zeroflags<<<8, 256, 0, stream>>>(FLAGS);
    k_swizzle<<<dim3(64,8), 64, 0, stream>>>(Wall_w, 1024, Wswz, 0);
    k_swizzle<<<dim3(16,8), 64, 0, stream>>>(Wd_w,    256, Wswz, 64);
    k_swizzle<<<dim3(64,8), 64, 0, stream>>>(Uall_w, 1024, Uswz, 0);
    k_swizzle<<<dim3(16,8), 64, 0, stream>>>(emb2_w,  256, Eswz, 0);
    k_swizzle<<<dim3(16,8), 64, 0, stream>>>(whk_w,   256, Hswz, 0);
    k_swizzle<<<dim3(16,2), 64, 0, stream>>>(time_w,  256, TWswz, 0);  // K=64 → q<2
    k_swizzle<<<dim3(4,8),  64, 0, stream>>>(w1_w + 256*64, 64, W1swz, 0);

    k_tft<<<3200, 64, 0, stream>>>(seq_time, sel_w, sel_b, TFT);
    k_cvt<<<12800, 256, 0, stream>>>(input_seqs, HS);          // f32 input → bf16 (staged in HS)
    k_gemm256<<<3200, 512, 0, stream>>>(HS, Eswz, emb2_b, X);
    k_ekcopy<<<256, 64, 0, stream>>>(X, EK);
    k_ekw<<<256, 64, 0, stream>>>(EK, w1_w, w1_b, EKW);
    k_gemmgates<<<3200, 512, 0, stream>>>(X, Uswz, Wall_b, Uall_b, XG);
    k_scan<<<32, 512, SCAN_LDS, stream>>>(XG, TFT, Wswz, TWswz, Wd_b, time_b, HS, MAXH1, 1,
                                          XBUF, FLAGS, 0u);
    k_gemm256<<<3200, 512, 0, stream>>>(HS, Hswz, whk_b, HS);   // whk in-place (block-local rows)
    k_gemm64<<<3200, 256, 0, stream>>>(HS, W1swz, W1P);         // whk @ w1[256:512] (f32)
    k_attn<<<6400, 512, 0, stream>>>(EK, HS, EKW, W1P, w2_w, w2_b, nn, pn, X);  // genx → X region
    k_gemmgates<<<3200, 512, 0, stream>>>(X, Uswz, Wall_b, Uall_b, XG);
    k_scan<<<32, 512, SCAN_LDS, stream>>>(XG, TFT, Wswz, TWswz, Wd_b, time_b, HS, MAXH2, 0,
                                          XBUF, FLAGS, (unsigned)SEQ);
    k_final<<<2, 512, 0, stream>>>(MAXH1, MAXH2, out_w, out_b, outp);
}